// Round 3
// baseline (1490.430 us; speedup 1.0000x reference)
//
#include <hip/hip_runtime.h>
#include <cstdint>
#include <cstddef>
#include <math.h>

// AtomSelector: B=4096, A=4096, H=768, L=4.
// R2: gates = bf16x2-split MFMA (3 products, verified exact-enough).
//     head  = plain bf16 MFMA (1 product) + exact fp32 refinement of the
//             top-8 gumbel-noised candidates inside sample_step.
//     gi+gh fused into one dispatch (A rows = [X; h] concatenated).
// PRNG: JAX threefry2x32 partitionable scheme (verified exact in R0).

#define KB 4096
#define KA 4096
#define KH 768
#define KL 4

typedef __attribute__((ext_vector_type(8))) short bf16x8;
typedef __attribute__((ext_vector_type(4))) float f32x4;

__host__ __device__ inline unsigned rotl32(unsigned x, int d) {
  return (x << d) | (x >> (32 - d));
}

// Threefry-2x32, 20 rounds
__host__ __device__ inline void tf2x32(unsigned k0, unsigned k1,
                                       unsigned x0, unsigned x1,
                                       unsigned& o0, unsigned& o1) {
  unsigned ks2 = k0 ^ k1 ^ 0x1BD11BDAu;
  x0 += k0; x1 += k1;
#define TF_R(r) { x0 += x1; x1 = rotl32(x1, (r)); x1 ^= x0; }
  TF_R(13) TF_R(15) TF_R(26) TF_R(6)
  x0 += k1;  x1 += ks2 + 1u;
  TF_R(17) TF_R(29) TF_R(16) TF_R(24)
  x0 += ks2; x1 += k0 + 2u;
  TF_R(13) TF_R(15) TF_R(26) TF_R(6)
  x0 += k0;  x1 += k1 + 3u;
  TF_R(17) TF_R(29) TF_R(16) TF_R(24)
  x0 += k1;  x1 += ks2 + 4u;
  TF_R(13) TF_R(15) TF_R(26) TF_R(6)
  x0 += ks2; x1 += k0 + 5u;
#undef TF_R
  o0 = x0; o1 = x1;
}

__device__ inline ushort f2bf(float f) {
  unsigned u = __float_as_uint(f);
  unsigned r = (u + 0x7fffu + ((u >> 16) & 1u)) >> 16;
  return (ushort)r;
}
__device__ inline float bf2f(ushort h) {
  return __uint_as_float(((unsigned)h) << 16);
}

// ---------------------------------------------------------------------------
// Fused gate GEMM: C = A @ W^T with A rows = [X(4096); h(4096)] (bf16x2 split,
// 3 products). blockIdx.y < 32 -> W=w_ih, C=Gi ; else W=w_hh, C=Gh.
// 256 thr / 4 waves; BM=BN=128, BK=64; wave -> 64x64 (4x4 of 16x16 tiles).
// LDS: 4 planes x 128x64 bf16 = 64KB, global_load_lds width=16, XOR-swizzled
// chunk slots (staging lane-contiguous; ds_read_b128 sees free 2-way only).
// ---------------------------------------------------------------------------
__global__ __launch_bounds__(256) void gemm3_cat(
    const ushort* __restrict__ AhiCat, const ushort* __restrict__ AloCat,
    const ushort* __restrict__ WihHi, const ushort* __restrict__ WihLo,
    const ushort* __restrict__ WhhHi, const ushort* __restrict__ WhhLo,
    float* __restrict__ Gi, float* __restrict__ Gh) {
  __shared__ ushort smem[4 * 128 * 64];
  const int tid = threadIdx.x;
  const int wave = tid >> 6;
  const int lane = tid & 63;
  const int by = blockIdx.y;
  const long long bm = (long long)by * 128;
  const long long bn = (long long)blockIdx.x * 128;
  const ushort* Bhi = (by < 32) ? WihHi : WhhHi;
  const ushort* Blo = (by < 32) ? WihLo : WhhLo;
  float* C = (by < 32) ? Gi : Gh;
  const long long cm0 = bm - ((by < 32) ? 0 : (long long)KB);
  const int wm = (wave & 1) * 64;
  const int wn = (wave >> 1) * 64;

  f32x4 acc[4][4];
#pragma unroll
  for (int i = 0; i < 4; ++i)
#pragma unroll
    for (int j = 0; j < 4; ++j) acc[i][j] = (f32x4){0.f, 0.f, 0.f, 0.f};

  const int r = lane >> 3;
  const int csrc = (lane & 7) ^ r;
  const int m15 = lane & 15;
  const int kg = (lane >> 4) & 3;

  for (int kt = 0; kt < 12; ++kt) {
    const int k0 = kt * 64;
#pragma unroll
    for (int s = 0; s < 4; ++s) {
      const int m0 = wave * 32 + s * 8;
      const long long arow = (bm + m0 + r) * KH + k0 + csrc * 8;
      const long long brow = (bn + m0 + r) * KH + k0 + csrc * 8;
      __builtin_amdgcn_global_load_lds(
          (const __attribute__((address_space(1))) void*)(AhiCat + arow),
          (__attribute__((address_space(3))) void*)&smem[0 * 8192 + m0 * 64], 16, 0, 0);
      __builtin_amdgcn_global_load_lds(
          (const __attribute__((address_space(1))) void*)(AloCat + arow),
          (__attribute__((address_space(3))) void*)&smem[1 * 8192 + m0 * 64], 16, 0, 0);
      __builtin_amdgcn_global_load_lds(
          (const __attribute__((address_space(1))) void*)(Bhi + brow),
          (__attribute__((address_space(3))) void*)&smem[2 * 8192 + m0 * 64], 16, 0, 0);
      __builtin_amdgcn_global_load_lds(
          (const __attribute__((address_space(1))) void*)(Blo + brow),
          (__attribute__((address_space(3))) void*)&smem[3 * 8192 + m0 * 64], 16, 0, 0);
    }
    __syncthreads();
#pragma unroll
    for (int ks = 0; ks < 2; ++ks) {
      bf16x8 ah[4], al[4], bh[4], bl[4];
#pragma unroll
      for (int i = 0; i < 4; ++i) {
        const int m = wm + i * 16 + m15;
        const int slot = (ks * 4 + kg) ^ (lane & 7);
        ah[i] = *(const bf16x8*)&smem[0 * 8192 + m * 64 + slot * 8];
        al[i] = *(const bf16x8*)&smem[1 * 8192 + m * 64 + slot * 8];
        const int n = wn + i * 16 + m15;
        bh[i] = *(const bf16x8*)&smem[2 * 8192 + n * 64 + slot * 8];
        bl[i] = *(const bf16x8*)&smem[3 * 8192 + n * 64 + slot * 8];
      }
#pragma unroll
      for (int i = 0; i < 4; ++i)
#pragma unroll
        for (int j = 0; j < 4; ++j) {
          acc[i][j] = __builtin_amdgcn_mfma_f32_16x16x32_bf16(ah[i], bh[j], acc[i][j], 0, 0, 0);
          acc[i][j] = __builtin_amdgcn_mfma_f32_16x16x32_bf16(ah[i], bl[j], acc[i][j], 0, 0, 0);
          acc[i][j] = __builtin_amdgcn_mfma_f32_16x16x32_bf16(al[i], bh[j], acc[i][j], 0, 0, 0);
        }
    }
    __syncthreads();
  }
  const int rq = (lane >> 4) * 4;
#pragma unroll
  for (int i = 0; i < 4; ++i)
#pragma unroll
    for (int j = 0; j < 4; ++j) {
      const long long n = bn + wn + j * 16 + m15;
#pragma unroll
      for (int rg = 0; rg < 4; ++rg) {
        const long long m = cm0 + wm + i * 16 + rq + rg;
        C[m * (3 * KH) + n] = acc[i][j][rg];
      }
    }
}

// ---------------------------------------------------------------------------
// Head GEMM: single-product bf16. C[M,N] = A[M,768] @ W[N,768]^T.
// Same structure, 2 LDS planes (32 KB).
// ---------------------------------------------------------------------------
__global__ __launch_bounds__(256) void gemm1_nt(
    const ushort* __restrict__ Ahi, const ushort* __restrict__ Bhi,
    float* __restrict__ C, long long ldc) {
  __shared__ ushort smem[2 * 128 * 64];
  const int tid = threadIdx.x;
  const int wave = tid >> 6;
  const int lane = tid & 63;
  const long long bm = (long long)blockIdx.y * 128;
  const long long bn = (long long)blockIdx.x * 128;
  const int wm = (wave & 1) * 64;
  const int wn = (wave >> 1) * 64;

  f32x4 acc[4][4];
#pragma unroll
  for (int i = 0; i < 4; ++i)
#pragma unroll
    for (int j = 0; j < 4; ++j) acc[i][j] = (f32x4){0.f, 0.f, 0.f, 0.f};

  const int r = lane >> 3;
  const int csrc = (lane & 7) ^ r;
  const int m15 = lane & 15;
  const int kg = (lane >> 4) & 3;

  for (int kt = 0; kt < 12; ++kt) {
    const int k0 = kt * 64;
#pragma unroll
    for (int s = 0; s < 4; ++s) {
      const int m0 = wave * 32 + s * 8;
      const long long arow = (bm + m0 + r) * KH + k0 + csrc * 8;
      const long long brow = (bn + m0 + r) * KH + k0 + csrc * 8;
      __builtin_amdgcn_global_load_lds(
          (const __attribute__((address_space(1))) void*)(Ahi + arow),
          (__attribute__((address_space(3))) void*)&smem[0 * 8192 + m0 * 64], 16, 0, 0);
      __builtin_amdgcn_global_load_lds(
          (const __attribute__((address_space(1))) void*)(Bhi + brow),
          (__attribute__((address_space(3))) void*)&smem[1 * 8192 + m0 * 64], 16, 0, 0);
    }
    __syncthreads();
#pragma unroll
    for (int ks = 0; ks < 2; ++ks) {
      bf16x8 ah[4], bh[4];
#pragma unroll
      for (int i = 0; i < 4; ++i) {
        const int m = wm + i * 16 + m15;
        const int slot = (ks * 4 + kg) ^ (lane & 7);
        ah[i] = *(const bf16x8*)&smem[0 * 8192 + m * 64 + slot * 8];
        const int n = wn + i * 16 + m15;
        bh[i] = *(const bf16x8*)&smem[1 * 8192 + n * 64 + slot * 8];
      }
#pragma unroll
      for (int i = 0; i < 4; ++i)
#pragma unroll
        for (int j = 0; j < 4; ++j)
          acc[i][j] = __builtin_amdgcn_mfma_f32_16x16x32_bf16(ah[i], bh[j], acc[i][j], 0, 0, 0);
    }
    __syncthreads();
  }
  const int rq = (lane >> 4) * 4;
#pragma unroll
  for (int i = 0; i < 4; ++i)
#pragma unroll
    for (int j = 0; j < 4; ++j) {
      const long long n = bn + wn + j * 16 + m15;
#pragma unroll
      for (int rg = 0; rg < 4; ++rg) {
        const long long m = bm + wm + i * 16 + rq + rg;
        C[m * ldc + n] = acc[i][j][rg];
      }
    }
}

// fp32 -> bf16 hi/lo planes (float4-vectorized; n4 = elems/4)
__global__ void convertf32(const float* __restrict__ src, ushort* __restrict__ hi,
                           ushort* __restrict__ lo, int n4) {
  int i = blockIdx.x * 256 + threadIdx.x;
  if (i >= n4) return;
  float4 v = ((const float4*)src)[i];
  ushort4 h, l;
  h.x = f2bf(v.x); l.x = f2bf(v.x - bf2f(h.x));
  h.y = f2bf(v.y); l.y = f2bf(v.y - bf2f(h.y));
  h.z = f2bf(v.z); l.z = f2bf(v.z - bf2f(h.z));
  h.w = f2bf(v.w); l.w = f2bf(v.w - bf2f(h.w));
  ((ushort4*)hi)[i] = h;
  ((ushort4*)lo)[i] = l;
}

// fp32 -> bf16 hi plane only
__global__ void convert_hi(const float* __restrict__ src, ushort* __restrict__ hi, int n4) {
  int i = blockIdx.x * 256 + threadIdx.x;
  if (i >= n4) return;
  float4 v = ((const float4*)src)[i];
  ushort4 h;
  h.x = f2bf(v.x); h.y = f2bf(v.y); h.z = f2bf(v.z); h.w = f2bf(v.w);
  ((ushort4*)hi)[i] = h;
}

// X[b,:] = cls[b,:] + ae_weight[idx[b],:]  -> bf16 hi/lo planes
__global__ void build_x(const float* __restrict__ cls, const float* __restrict__ aew,
                        const int* __restrict__ idxbuf, ushort* __restrict__ Xhi,
                        ushort* __restrict__ Xlo) {
  int i = blockIdx.x * 256 + threadIdx.x;  // over B*H/4
  int b = i / (KH / 4);
  int c = i - b * (KH / 4);
  int idx = idxbuf[b];
  float4 cv = ((const float4*)cls)[i];
  float4 av = ((const float4*)(aew + (size_t)idx * KH))[c];
  float4 x = make_float4(cv.x + av.x, cv.y + av.y, cv.z + av.z, cv.w + av.w);
  ushort4 h, l;
  h.x = f2bf(x.x); l.x = f2bf(x.x - bf2f(h.x));
  h.y = f2bf(x.y); l.y = f2bf(x.y - bf2f(h.y));
  h.z = f2bf(x.z); l.z = f2bf(x.z - bf2f(h.z));
  h.w = f2bf(x.w); l.w = f2bf(x.w - bf2f(h.w));
  ((ushort4*)Xhi)[i] = h;
  ((ushort4*)Xlo)[i] = l;
}

// GRU gates; h (fp32) updated in place, bf16 hi/lo planes written too.
__global__ void gru_gate(const float* __restrict__ Gi, const float* __restrict__ Gh,
                         const float* __restrict__ b_ih, const float* __restrict__ b_hh,
                         float* __restrict__ h, ushort* __restrict__ hHi,
                         ushort* __restrict__ hLo, int first) {
  int i = blockIdx.x * 256 + threadIdx.x;  // over B*H
  int b = i / KH, c = i - b * KH;
  const float* gi = Gi + (size_t)b * (3 * KH);
  float ir  = gi[c]          + b_ih[c];
  float iz  = gi[c + KH]     + b_ih[c + KH];
  float in_ = gi[c + 2 * KH] + b_ih[c + 2 * KH];
  float hr = b_hh[c], hz = b_hh[c + KH], hn = b_hh[c + 2 * KH];
  float hp = 0.f;
  if (!first) {
    const float* gh = Gh + (size_t)b * (3 * KH);
    hr += gh[c]; hz += gh[c + KH]; hn += gh[c + 2 * KH];
    hp = h[i];
  }
  float rr = 1.f / (1.f + expf(-(ir + hr)));
  float z = 1.f / (1.f + expf(-(iz + hz)));
  float n = tanhf(in_ + rr * hn);
  float hv = (1.f - z) * n + z * hp;
  h[i] = hv;
  ushort hh = f2bf(hv);
  hHi[i] = hh;
  hLo[i] = f2bf(hv - bf2f(hh));
}

// One block per batch row: gumbel + mask machine + bf16 top-8 -> exact fp32
// refinement of the 8 candidates -> argmax -> one-hot.
__global__ __launch_bounds__(256) void sample_step(
    float* __restrict__ out, const float* __restrict__ head_b,
    const float* __restrict__ x_, unsigned char* __restrict__ mask,
    int* __restrict__ idxbuf, const float* __restrict__ hbuf,
    const float* __restrict__ head_w, int j, unsigned s0, unsigned s1) {
  const int b = blockIdx.x;
  const int tid = threadIdx.x;
  float* orow = out + ((size_t)b * KL + j) * KA;
  unsigned char* mrow = mask + (size_t)b * KA;
  const float* xrow = x_ + (size_t)b * KA;
  __shared__ float vals[KA];
  __shared__ float sv[256];
  __shared__ int si[256];
  __shared__ int scand[8];
  __shared__ float srefined[8];

  int idx_prev = 0;
  if (j > 0) idx_prev = idxbuf[b];

  int empty = 0;
  if (j == 0) {
    int cnt = 0;
#pragma unroll
    for (int t = 0; t < 16; ++t) cnt += (xrow[tid + (t << 8)] != 0.f) ? 1 : 0;
    si[tid] = cnt;
    __syncthreads();
    for (int s = 128; s > 0; s >>= 1) {
      if (tid < s) si[tid] += si[tid + s];
      __syncthreads();
    }
    empty = (si[0] == 0);
    __syncthreads();
  }

  // Phase 1: approx candidate values (bf16 logit + bias + gumbel) into LDS.
  unsigned mbits = 0;
#pragma unroll
  for (int t = 0; t < 16; ++t) {
    int a = tid + (t << 8);
    int m;
    if (j == 0) {
      m = (xrow[a] != 0.f) ? 1 : 0;
      if (empty && a == 0) m = 1;
    } else {
      m = mrow[a];
      if (idx_prev == 0) m = 0;
      if (a == 0) m = 1;
    }
    float v = -INFINITY;
    if (m) {
      unsigned o0, o1;
      tf2x32(s0, s1, 0u, (unsigned)(b * KA + a), o0, o1);
      unsigned bits = o0 ^ o1;
      float f = __uint_as_float((bits >> 9) | 0x3f800000u) - 1.0f;
      const float TINY = 1.17549435e-38f;
      float u = fmaxf(TINY, f + TINY);
      float g = -logf(-logf(u));
      v = orow[a] + head_b[a] + g;
      mbits |= (1u << t);
    }
    vals[a] = v;
  }
  __syncthreads();

  // Phase 2: top-8 by approx value (first-index tie-break).
  for (int t = 0; t < 8; ++t) {
    float best = -INFINITY;
    int bi = KA;
#pragma unroll
    for (int u = 0; u < 16; ++u) {
      int a = tid + (u << 8);
      float v = vals[a];
      if (v > best || (v == best && a < bi)) { best = v; bi = a; }
    }
    sv[tid] = best; si[tid] = bi;
    __syncthreads();
    for (int s = 128; s > 0; s >>= 1) {
      if (tid < s) {
        float v2 = sv[tid + s]; int i2 = si[tid + s];
        if (v2 > sv[tid] || (v2 == sv[tid] && i2 < si[tid])) { sv[tid] = v2; si[tid] = i2; }
      }
      __syncthreads();
    }
    if (tid == 0) {
      int sel = (sv[0] == -INFINITY) ? -1 : si[0];
      scand[t] = sel;
      if (sel >= 0) vals[sel] = -INFINITY;
    }
    __syncthreads();
  }

  // Phase 3: exact fp32 refinement of the 8 candidates.
  // wave w handles candidates 2w (lanes 0-31) and 2w+1 (lanes 32-63).
  {
    const int wv = tid >> 6;
    const int lane = tid & 63;
    const int half = lane >> 5;
    const int l32 = lane & 31;
    const int t = wv * 2 + half;
    const int a = scand[t];
    float sum = 0.f;
    if (a >= 0) {
      const float4* h4 = (const float4*)(hbuf + (size_t)b * KH);
      const float4* w4 = (const float4*)(head_w + (size_t)a * KH);
#pragma unroll
      for (int u = 0; u < 6; ++u) {
        float4 hv = h4[l32 + u * 32];
        float4 wv4 = w4[l32 + u * 32];
        sum = fmaf(hv.x, wv4.x, sum);
        sum = fmaf(hv.y, wv4.y, sum);
        sum = fmaf(hv.z, wv4.z, sum);
        sum = fmaf(hv.w, wv4.w, sum);
      }
    }
#pragma unroll
    for (int off = 16; off > 0; off >>= 1) sum += __shfl_down(sum, off, 32);
    if (l32 == 0) {
      float rv = -INFINITY;
      if (a >= 0) {
        unsigned o0, o1;
        tf2x32(s0, s1, 0u, (unsigned)(b * KA + a), o0, o1);
        unsigned bits = o0 ^ o1;
        float f = __uint_as_float((bits >> 9) | 0x3f800000u) - 1.0f;
        const float TINY = 1.17549435e-38f;
        float u = fmaxf(TINY, f + TINY);
        float g = -logf(-logf(u));
        rv = sum + head_b[a] + g;
      }
      srefined[t] = rv;
    }
  }
  __syncthreads();

  // Phase 4: final argmax over refined candidates (lower index on ties).
  if (tid == 0) {
    float best = -INFINITY;
    int bsel = KA;
    for (int t = 0; t < 8; ++t) {
      float v = srefined[t];
      int a = scand[t];
      if (a >= 0 && (v > best || (v == best && a < bsel))) { best = v; bsel = a; }
    }
    si[0] = bsel;
  }
  __syncthreads();
  const int sel = si[0];

  // Phase 5: one-hot + mask update.
#pragma unroll
  for (int t = 0; t < 16; ++t) {
    int a = tid + (t << 8);
    int m = (mbits >> t) & 1;
    if (a == sel) m = 0;
    mrow[a] = (unsigned char)m;
    orow[a] = (a == sel) ? 1.f : 0.f;
  }
  if (tid == 0) idxbuf[b] = sel;
}

extern "C" void kernel_launch(void* const* d_in, const int* in_sizes, int n_in,
                              void* d_out, int out_size, void* d_ws, size_t ws_size,
                              hipStream_t stream) {
  const float* cls    = (const float*)d_in[0];
  const float* x_     = (const float*)d_in[1];
  const float* w_ih   = (const float*)d_in[2];
  const float* w_hh   = (const float*)d_in[3];
  const float* b_ih   = (const float*)d_in[4];
  const float* b_hh   = (const float*)d_in[5];
  const float* head_w = (const float*)d_in[6];
  const float* head_b = (const float*)d_in[7];
  const float* ae_w   = (const float*)d_in[8];
  float* out = (float*)d_out;

  char* p = (char*)d_ws;
  // A-concat planes: rows [0,4096) = X, rows [4096,8192) = h.
  ushort* XhiCat = (ushort*)p; p += (size_t)2 * KB * KH * 2;   // 12.6 MB
  ushort* XloCat = (ushort*)p; p += (size_t)2 * KB * KH * 2;   // 12.6 MB
  ushort* Xhi = XhiCat;
  ushort* Xlo = XloCat;
  ushort* hHi = XhiCat + (size_t)KB * KH;
  ushort* hLo = XloCat + (size_t)KB * KH;
  float*  hbuf  = (float*)p;  p += (size_t)KB * KH * 4;        // 12.6 MB
  ushort* WihHi = (ushort*)p; p += (size_t)3 * KH * KH * 2;    // 3.5 MB
  ushort* WihLo = (ushort*)p; p += (size_t)3 * KH * KH * 2;
  ushort* WhhHi = (ushort*)p; p += (size_t)3 * KH * KH * 2;
  ushort* WhhLo = (ushort*)p; p += (size_t)3 * KH * KH * 2;
  ushort* HwHi  = (ushort*)p; p += (size_t)KA * KH * 2;        // 6.3 MB
  float*  Gi    = (float*)p;  p += (size_t)KB * 3 * KH * 4;    // 37.7 MB
  float*  Gh    = (float*)p;  p += (size_t)KB * 3 * KH * 4;    // 37.7 MB
  unsigned char* mask = (unsigned char*)p; p += (size_t)KB * KA;  // 16.8 MB
  int* idxbuf = (int*)p; p += (size_t)KB * 4;

  // Host-side JAX key schedule (partitionable split of key(42)).
  unsigned key0 = 0u, key1 = 42u;
  unsigned sub0[KL], sub1[KL];
  for (int j = 0; j < KL; ++j) {
    unsigned n0, n1, t0, t1;
    tf2x32(key0, key1, 0u, 0u, n0, n1);
    tf2x32(key0, key1, 0u, 1u, t0, t1);
    sub0[j] = t0; sub1[j] = t1;
    key0 = n0; key1 = n1;
  }

  // Split weights once per launch.
  convertf32<<<(3 * KH * KH / 4 + 255) / 256, 256, 0, stream>>>(w_ih, WihHi, WihLo, 3 * KH * KH / 4);
  convertf32<<<(3 * KH * KH / 4 + 255) / 256, 256, 0, stream>>>(w_hh, WhhHi, WhhLo, 3 * KH * KH / 4);
  convert_hi<<<(KA * KH / 4 + 255) / 256, 256, 0, stream>>>(head_w, HwHi, KA * KH / 4);

  for (int j = 0; j < KL; ++j) {
    if (j == 0)
      convertf32<<<(KB * KH / 4 + 255) / 256, 256, 0, stream>>>(cls, Xhi, Xlo, KB * KH / 4);
    else
      build_x<<<KB * KH / 4 / 256, 256, 0, stream>>>(cls, ae_w, idxbuf, Xhi, Xlo);
    // gi (+ gh when j>0) in ONE dispatch over the concatenated A rows.
    gemm3_cat<<<dim3(3 * KH / 128, j == 0 ? 32 : 64), 256, 0, stream>>>(
        XhiCat, XloCat, WihHi, WihLo, WhhHi, WhhLo, Gi, Gh);
    gru_gate<<<KB * KH / 256, 256, 0, stream>>>(Gi, Gh, b_ih, b_hh, hbuf, hHi, hLo, j == 0);
    // approx logits (bf16 single product) straight into d_out[:, j, :]
    gemm1_nt<<<dim3(KA / 128, KB / 128), 256, 0, stream>>>(hHi, HwHi,
                                                           out + (size_t)j * KA, (long long)KL * KA);
    sample_step<<<KB, 256, 0, stream>>>(out, head_b, x_, mask, idxbuf, hbuf,
                                        head_w, j, sub0[j], sub1[j]);
  }
}

// Round 4
// 1210.342 us; speedup vs baseline: 1.2314x; 1.2314x over previous
//
#include <hip/hip_runtime.h>
#include <cstdint>
#include <cstddef>
#include <math.h>

// AtomSelector: B=4096, A=4096, H=768, L=4.
// R4: gates = bf16x2-split MFMA (3 products); head = plain bf16 MFMA +
//     exact fp32 refinement of eps-window candidates (one-pass collection,
//     typically exactly 1 candidate). gi+gh fused in one dispatch.
// PRNG: JAX threefry2x32 partitionable scheme (verified exact in R0).

#define KB 4096
#define KA 4096
#define KH 768
#define KL 4

typedef __attribute__((ext_vector_type(8))) short bf16x8;
typedef __attribute__((ext_vector_type(4))) float f32x4;

__host__ __device__ inline unsigned rotl32(unsigned x, int d) {
  return (x << d) | (x >> (32 - d));
}

// Threefry-2x32, 20 rounds
__host__ __device__ inline void tf2x32(unsigned k0, unsigned k1,
                                       unsigned x0, unsigned x1,
                                       unsigned& o0, unsigned& o1) {
  unsigned ks2 = k0 ^ k1 ^ 0x1BD11BDAu;
  x0 += k0; x1 += k1;
#define TF_R(r) { x0 += x1; x1 = rotl32(x1, (r)); x1 ^= x0; }
  TF_R(13) TF_R(15) TF_R(26) TF_R(6)
  x0 += k1;  x1 += ks2 + 1u;
  TF_R(17) TF_R(29) TF_R(16) TF_R(24)
  x0 += ks2; x1 += k0 + 2u;
  TF_R(13) TF_R(15) TF_R(26) TF_R(6)
  x0 += k0;  x1 += k1 + 3u;
  TF_R(17) TF_R(29) TF_R(16) TF_R(24)
  x0 += k1;  x1 += ks2 + 4u;
  TF_R(13) TF_R(15) TF_R(26) TF_R(6)
  x0 += ks2; x1 += k0 + 5u;
#undef TF_R
  o0 = x0; o1 = x1;
}

__device__ inline ushort f2bf(float f) {
  unsigned u = __float_as_uint(f);
  unsigned r = (u + 0x7fffu + ((u >> 16) & 1u)) >> 16;
  return (ushort)r;
}
__device__ inline float bf2f(ushort h) {
  return __uint_as_float(((unsigned)h) << 16);
}

__device__ inline float gumbel_at(unsigned s0, unsigned s1, unsigned ctr) {
  unsigned o0, o1;
  tf2x32(s0, s1, 0u, ctr, o0, o1);
  unsigned bits = o0 ^ o1;
  float f = __uint_as_float((bits >> 9) | 0x3f800000u) - 1.0f;
  const float TINY = 1.17549435e-38f;
  float u = fmaxf(TINY, f + TINY);
  return -logf(-logf(u));
}

// ---------------------------------------------------------------------------
// Fused gate GEMM: C = A @ W^T with A rows = [X(4096); h(4096)] (bf16x2 split,
// 3 products). blockIdx.y < 32 -> W=w_ih, C=Gi ; else W=w_hh, C=Gh.
// ---------------------------------------------------------------------------
__global__ __launch_bounds__(256) void gemm3_cat(
    const ushort* __restrict__ AhiCat, const ushort* __restrict__ AloCat,
    const ushort* __restrict__ WihHi, const ushort* __restrict__ WihLo,
    const ushort* __restrict__ WhhHi, const ushort* __restrict__ WhhLo,
    float* __restrict__ Gi, float* __restrict__ Gh) {
  __shared__ ushort smem[4 * 128 * 64];
  const int tid = threadIdx.x;
  const int wave = tid >> 6;
  const int lane = tid & 63;
  const int by = blockIdx.y;
  const long long bm = (long long)by * 128;
  const long long bn = (long long)blockIdx.x * 128;
  const ushort* Bhi = (by < 32) ? WihHi : WhhHi;
  const ushort* Blo = (by < 32) ? WihLo : WhhLo;
  float* C = (by < 32) ? Gi : Gh;
  const long long cm0 = bm - ((by < 32) ? 0 : (long long)KB);
  const int wm = (wave & 1) * 64;
  const int wn = (wave >> 1) * 64;

  f32x4 acc[4][4];
#pragma unroll
  for (int i = 0; i < 4; ++i)
#pragma unroll
    for (int j = 0; j < 4; ++j) acc[i][j] = (f32x4){0.f, 0.f, 0.f, 0.f};

  const int r = lane >> 3;
  const int csrc = (lane & 7) ^ r;
  const int m15 = lane & 15;
  const int kg = (lane >> 4) & 3;

  for (int kt = 0; kt < 12; ++kt) {
    const int k0 = kt * 64;
#pragma unroll
    for (int s = 0; s < 4; ++s) {
      const int m0 = wave * 32 + s * 8;
      const long long arow = (bm + m0 + r) * KH + k0 + csrc * 8;
      const long long brow = (bn + m0 + r) * KH + k0 + csrc * 8;
      __builtin_amdgcn_global_load_lds(
          (const __attribute__((address_space(1))) void*)(AhiCat + arow),
          (__attribute__((address_space(3))) void*)&smem[0 * 8192 + m0 * 64], 16, 0, 0);
      __builtin_amdgcn_global_load_lds(
          (const __attribute__((address_space(1))) void*)(AloCat + arow),
          (__attribute__((address_space(3))) void*)&smem[1 * 8192 + m0 * 64], 16, 0, 0);
      __builtin_amdgcn_global_load_lds(
          (const __attribute__((address_space(1))) void*)(Bhi + brow),
          (__attribute__((address_space(3))) void*)&smem[2 * 8192 + m0 * 64], 16, 0, 0);
      __builtin_amdgcn_global_load_lds(
          (const __attribute__((address_space(1))) void*)(Blo + brow),
          (__attribute__((address_space(3))) void*)&smem[3 * 8192 + m0 * 64], 16, 0, 0);
    }
    __syncthreads();
#pragma unroll
    for (int ks = 0; ks < 2; ++ks) {
      bf16x8 ah[4], al[4], bh[4], bl[4];
#pragma unroll
      for (int i = 0; i < 4; ++i) {
        const int m = wm + i * 16 + m15;
        const int slot = (ks * 4 + kg) ^ (lane & 7);
        ah[i] = *(const bf16x8*)&smem[0 * 8192 + m * 64 + slot * 8];
        al[i] = *(const bf16x8*)&smem[1 * 8192 + m * 64 + slot * 8];
        const int n = wn + i * 16 + m15;
        bh[i] = *(const bf16x8*)&smem[2 * 8192 + n * 64 + slot * 8];
        bl[i] = *(const bf16x8*)&smem[3 * 8192 + n * 64 + slot * 8];
      }
#pragma unroll
      for (int i = 0; i < 4; ++i)
#pragma unroll
        for (int j = 0; j < 4; ++j) {
          acc[i][j] = __builtin_amdgcn_mfma_f32_16x16x32_bf16(ah[i], bh[j], acc[i][j], 0, 0, 0);
          acc[i][j] = __builtin_amdgcn_mfma_f32_16x16x32_bf16(ah[i], bl[j], acc[i][j], 0, 0, 0);
          acc[i][j] = __builtin_amdgcn_mfma_f32_16x16x32_bf16(al[i], bh[j], acc[i][j], 0, 0, 0);
        }
    }
    __syncthreads();
  }
  const int rq = (lane >> 4) * 4;
#pragma unroll
  for (int i = 0; i < 4; ++i)
#pragma unroll
    for (int j = 0; j < 4; ++j) {
      const long long n = bn + wn + j * 16 + m15;
#pragma unroll
      for (int rg = 0; rg < 4; ++rg) {
        const long long m = cm0 + wm + i * 16 + rq + rg;
        C[m * (3 * KH) + n] = acc[i][j][rg];
      }
    }
}

// ---------------------------------------------------------------------------
// Head GEMM: single-product bf16. C[M,N] = A[M,768] @ W[N,768]^T.
// ---------------------------------------------------------------------------
__global__ __launch_bounds__(256) void gemm1_nt(
    const ushort* __restrict__ Ahi, const ushort* __restrict__ Bhi,
    float* __restrict__ C, long long ldc) {
  __shared__ ushort smem[2 * 128 * 64];
  const int tid = threadIdx.x;
  const int wave = tid >> 6;
  const int lane = tid & 63;
  const long long bm = (long long)blockIdx.y * 128;
  const long long bn = (long long)blockIdx.x * 128;
  const int wm = (wave & 1) * 64;
  const int wn = (wave >> 1) * 64;

  f32x4 acc[4][4];
#pragma unroll
  for (int i = 0; i < 4; ++i)
#pragma unroll
    for (int j = 0; j < 4; ++j) acc[i][j] = (f32x4){0.f, 0.f, 0.f, 0.f};

  const int r = lane >> 3;
  const int csrc = (lane & 7) ^ r;
  const int m15 = lane & 15;
  const int kg = (lane >> 4) & 3;

  for (int kt = 0; kt < 12; ++kt) {
    const int k0 = kt * 64;
#pragma unroll
    for (int s = 0; s < 4; ++s) {
      const int m0 = wave * 32 + s * 8;
      const long long arow = (bm + m0 + r) * KH + k0 + csrc * 8;
      const long long brow = (bn + m0 + r) * KH + k0 + csrc * 8;
      __builtin_amdgcn_global_load_lds(
          (const __attribute__((address_space(1))) void*)(Ahi + arow),
          (__attribute__((address_space(3))) void*)&smem[0 * 8192 + m0 * 64], 16, 0, 0);
      __builtin_amdgcn_global_load_lds(
          (const __attribute__((address_space(1))) void*)(Bhi + brow),
          (__attribute__((address_space(3))) void*)&smem[1 * 8192 + m0 * 64], 16, 0, 0);
    }
    __syncthreads();
#pragma unroll
    for (int ks = 0; ks < 2; ++ks) {
      bf16x8 ah[4], bh[4];
#pragma unroll
      for (int i = 0; i < 4; ++i) {
        const int m = wm + i * 16 + m15;
        const int slot = (ks * 4 + kg) ^ (lane & 7);
        ah[i] = *(const bf16x8*)&smem[0 * 8192 + m * 64 + slot * 8];
        const int n = wn + i * 16 + m15;
        bh[i] = *(const bf16x8*)&smem[1 * 8192 + n * 64 + slot * 8];
      }
#pragma unroll
      for (int i = 0; i < 4; ++i)
#pragma unroll
        for (int j = 0; j < 4; ++j)
          acc[i][j] = __builtin_amdgcn_mfma_f32_16x16x32_bf16(ah[i], bh[j], acc[i][j], 0, 0, 0);
    }
    __syncthreads();
  }
  const int rq = (lane >> 4) * 4;
#pragma unroll
  for (int i = 0; i < 4; ++i)
#pragma unroll
    for (int j = 0; j < 4; ++j) {
      const long long n = bn + wn + j * 16 + m15;
#pragma unroll
      for (int rg = 0; rg < 4; ++rg) {
        const long long m = bm + wm + i * 16 + rq + rg;
        C[m * ldc + n] = acc[i][j][rg];
      }
    }
}

// fp32 -> bf16 hi/lo planes (float4-vectorized; n4 = elems/4)
__global__ void convertf32(const float* __restrict__ src, ushort* __restrict__ hi,
                           ushort* __restrict__ lo, int n4) {
  int i = blockIdx.x * 256 + threadIdx.x;
  if (i >= n4) return;
  float4 v = ((const float4*)src)[i];
  ushort4 h, l;
  h.x = f2bf(v.x); l.x = f2bf(v.x - bf2f(h.x));
  h.y = f2bf(v.y); l.y = f2bf(v.y - bf2f(h.y));
  h.z = f2bf(v.z); l.z = f2bf(v.z - bf2f(h.z));
  h.w = f2bf(v.w); l.w = f2bf(v.w - bf2f(h.w));
  ((ushort4*)hi)[i] = h;
  ((ushort4*)lo)[i] = l;
}

// fp32 -> bf16 hi plane only
__global__ void convert_hi(const float* __restrict__ src, ushort* __restrict__ hi, int n4) {
  int i = blockIdx.x * 256 + threadIdx.x;
  if (i >= n4) return;
  float4 v = ((const float4*)src)[i];
  ushort4 h;
  h.x = f2bf(v.x); h.y = f2bf(v.y); h.z = f2bf(v.z); h.w = f2bf(v.w);
  ((ushort4*)hi)[i] = h;
}

// X[b,:] = cls[b,:] + ae_weight[idx[b],:]  -> bf16 hi/lo planes
__global__ void build_x(const float* __restrict__ cls, const float* __restrict__ aew,
                        const int* __restrict__ idxbuf, ushort* __restrict__ Xhi,
                        ushort* __restrict__ Xlo) {
  int i = blockIdx.x * 256 + threadIdx.x;  // over B*H/4
  int b = i / (KH / 4);
  int c = i - b * (KH / 4);
  int idx = idxbuf[b];
  float4 cv = ((const float4*)cls)[i];
  float4 av = ((const float4*)(aew + (size_t)idx * KH))[c];
  float4 x = make_float4(cv.x + av.x, cv.y + av.y, cv.z + av.z, cv.w + av.w);
  ushort4 h, l;
  h.x = f2bf(x.x); l.x = f2bf(x.x - bf2f(h.x));
  h.y = f2bf(x.y); l.y = f2bf(x.y - bf2f(h.y));
  h.z = f2bf(x.z); l.z = f2bf(x.z - bf2f(h.z));
  h.w = f2bf(x.w); l.w = f2bf(x.w - bf2f(h.w));
  ((ushort4*)Xhi)[i] = h;
  ((ushort4*)Xlo)[i] = l;
}

// GRU gates; h (fp32) updated in place, bf16 hi/lo planes written too.
__global__ void gru_gate(const float* __restrict__ Gi, const float* __restrict__ Gh,
                         const float* __restrict__ b_ih, const float* __restrict__ b_hh,
                         float* __restrict__ h, ushort* __restrict__ hHi,
                         ushort* __restrict__ hLo, int first) {
  int i = blockIdx.x * 256 + threadIdx.x;  // over B*H
  int b = i / KH, c = i - b * KH;
  const float* gi = Gi + (size_t)b * (3 * KH);
  float ir  = gi[c]          + b_ih[c];
  float iz  = gi[c + KH]     + b_ih[c + KH];
  float in_ = gi[c + 2 * KH] + b_ih[c + 2 * KH];
  float hr = b_hh[c], hz = b_hh[c + KH], hn = b_hh[c + 2 * KH];
  float hp = 0.f;
  if (!first) {
    const float* gh = Gh + (size_t)b * (3 * KH);
    hr += gh[c]; hz += gh[c + KH]; hn += gh[c + 2 * KH];
    hp = h[i];
  }
  float rr = 1.f / (1.f + expf(-(ir + hr)));
  float z = 1.f / (1.f + expf(-(iz + hz)));
  float n = tanhf(in_ + rr * hn);
  float hv = (1.f - z) * n + z * hp;
  h[i] = hv;
  ushort hh = f2bf(hv);
  hHi[i] = hh;
  hLo[i] = f2bf(hv - bf2f(hh));
}

// One block per batch row: approx vals in REGISTERS, single max-reduction,
// eps-window candidate collection (usually 1 candidate), exact fp32
// refinement, one-hot write.
__global__ __launch_bounds__(256) void sample_step(
    float* __restrict__ out, const float* __restrict__ head_b,
    const float* __restrict__ x_, unsigned char* __restrict__ mask,
    int* __restrict__ idxbuf, const float* __restrict__ hbuf,
    const float* __restrict__ head_w, int j, unsigned s0, unsigned s1) {
  const int b = blockIdx.x;
  const int tid = threadIdx.x;
  float* orow = out + ((size_t)b * KL + j) * KA;
  unsigned char* mrow = mask + (size_t)b * KA;
  const float* xrow = x_ + (size_t)b * KA;
  __shared__ float sv[256];
  __shared__ int si[256];
  __shared__ int scand[16];
  __shared__ float srefined[16];
  __shared__ int scnt;
  __shared__ int ssel;
  const float EPS = 0.01f;  // >> 2x bf16 logit error bound (~4e-3)

  if (tid == 0) scnt = 0;

  int idx_prev = 0;
  if (j > 0) idx_prev = idxbuf[b];

  int empty = 0;
  if (j == 0) {
    int cnt = 0;
#pragma unroll
    for (int t = 0; t < 16; ++t) cnt += (xrow[tid + (t << 8)] != 0.f) ? 1 : 0;
    si[tid] = cnt;
    __syncthreads();
    for (int s = 128; s > 0; s >>= 1) {
      if (tid < s) si[tid] += si[tid + s];
      __syncthreads();
    }
    empty = (si[0] == 0);
    __syncthreads();
  }

  // Phase 1: approx candidate values into registers.
  float vreg[16];
  unsigned mbits = 0;
  float lmax = -INFINITY;
#pragma unroll
  for (int t = 0; t < 16; ++t) {
    int a = tid + (t << 8);
    int m;
    if (j == 0) {
      m = (xrow[a] != 0.f) ? 1 : 0;
      if (empty && a == 0) m = 1;
    } else {
      m = mrow[a];
      if (idx_prev == 0) m = 0;
      if (a == 0) m = 1;
    }
    float v = -INFINITY;
    if (m) {
      float g = gumbel_at(s0, s1, (unsigned)(b * KA + a));
      v = orow[a] + head_b[a] + g;
      mbits |= (1u << t);
    }
    vreg[t] = v;
    lmax = fmaxf(lmax, v);
  }
  // Phase 2: single block max-reduction.
  sv[tid] = lmax;
  __syncthreads();
  for (int s = 128; s > 0; s >>= 1) {
    if (tid < s) sv[tid] = fmaxf(sv[tid], sv[tid + s]);
    __syncthreads();
  }
  const float vmax = sv[0];

  // Phase 3: collect eps-window candidates (<=16; typically 1).
  const float thresh = vmax - EPS;
#pragma unroll
  for (int t = 0; t < 16; ++t) {
    if (vreg[t] >= thresh) {
      int slot = atomicAdd(&scnt, 1);
      if (slot < 16) scand[slot] = tid + (t << 8);
    }
  }
  __syncthreads();
  const int ncand = min(scnt, 16);

  // Phase 4: exact fp32 refinement; wave w handles candidates w, w+4, ...
  {
    const int wv = tid >> 6;
    const int lane = tid & 63;
    const float4* h4 = (const float4*)(hbuf + (size_t)b * KH);
    for (int t = wv; t < ncand; t += 4) {
      const int a = scand[t];
      const float4* w4 = (const float4*)(head_w + (size_t)a * KH);
      float sum = 0.f;
#pragma unroll
      for (int u = 0; u < 3; ++u) {  // 768/4 = 192 float4 over 64 lanes
        float4 hv = h4[lane + u * 64];
        float4 wv4 = w4[lane + u * 64];
        sum = fmaf(hv.x, wv4.x, sum);
        sum = fmaf(hv.y, wv4.y, sum);
        sum = fmaf(hv.z, wv4.z, sum);
        sum = fmaf(hv.w, wv4.w, sum);
      }
#pragma unroll
      for (int off = 32; off > 0; off >>= 1) sum += __shfl_down(sum, off);
      if (lane == 0) {
        float g = gumbel_at(s0, s1, (unsigned)(b * KA + a));
        srefined[t] = sum + head_b[a] + g;
      }
    }
  }
  __syncthreads();

  // Phase 5: final argmax over refined candidates (lower index on ties).
  if (tid == 0) {
    float best = -INFINITY;
    int bsel = KA;
    for (int t = 0; t < ncand; ++t) {
      float v = srefined[t];
      int a = scand[t];
      if (v > best || (v == best && a < bsel)) { best = v; bsel = a; }
    }
    ssel = bsel;
  }
  __syncthreads();
  const int sel = ssel;

  // Phase 6: one-hot + mask update.
#pragma unroll
  for (int t = 0; t < 16; ++t) {
    int a = tid + (t << 8);
    int m = (mbits >> t) & 1;
    if (a == sel) m = 0;
    mrow[a] = (unsigned char)m;
    orow[a] = (a == sel) ? 1.f : 0.f;
  }
  if (tid == 0) idxbuf[b] = sel;
}

extern "C" void kernel_launch(void* const* d_in, const int* in_sizes, int n_in,
                              void* d_out, int out_size, void* d_ws, size_t ws_size,
                              hipStream_t stream) {
  const float* cls    = (const float*)d_in[0];
  const float* x_     = (const float*)d_in[1];
  const float* w_ih   = (const float*)d_in[2];
  const float* w_hh   = (const float*)d_in[3];
  const float* b_ih   = (const float*)d_in[4];
  const float* b_hh   = (const float*)d_in[5];
  const float* head_w = (const float*)d_in[6];
  const float* head_b = (const float*)d_in[7];
  const float* ae_w   = (const float*)d_in[8];
  float* out = (float*)d_out;

  char* p = (char*)d_ws;
  // A-concat planes: rows [0,4096) = X, rows [4096,8192) = h.
  ushort* XhiCat = (ushort*)p; p += (size_t)2 * KB * KH * 2;   // 12.6 MB
  ushort* XloCat = (ushort*)p; p += (size_t)2 * KB * KH * 2;   // 12.6 MB
  ushort* Xhi = XhiCat;
  ushort* Xlo = XloCat;
  ushort* hHi = XhiCat + (size_t)KB * KH;
  ushort* hLo = XloCat + (size_t)KB * KH;
  float*  hbuf  = (float*)p;  p += (size_t)KB * KH * 4;        // 12.6 MB
  ushort* WihHi = (ushort*)p; p += (size_t)3 * KH * KH * 2;    // 3.5 MB
  ushort* WihLo = (ushort*)p; p += (size_t)3 * KH * KH * 2;
  ushort* WhhHi = (ushort*)p; p += (size_t)3 * KH * KH * 2;
  ushort* WhhLo = (ushort*)p; p += (size_t)3 * KH * KH * 2;
  ushort* HwHi  = (ushort*)p; p += (size_t)KA * KH * 2;        // 6.3 MB
  float*  Gi    = (float*)p;  p += (size_t)KB * 3 * KH * 4;    // 37.7 MB
  float*  Gh    = (float*)p;  p += (size_t)KB * 3 * KH * 4;    // 37.7 MB
  unsigned char* mask = (unsigned char*)p; p += (size_t)KB * KA;  // 16.8 MB
  int* idxbuf = (int*)p; p += (size_t)KB * 4;

  // Host-side JAX key schedule (partitionable split of key(42)).
  unsigned key0 = 0u, key1 = 42u;
  unsigned sub0[KL], sub1[KL];
  for (int j = 0; j < KL; ++j) {
    unsigned n0, n1, t0, t1;
    tf2x32(key0, key1, 0u, 0u, n0, n1);
    tf2x32(key0, key1, 0u, 1u, t0, t1);
    sub0[j] = t0; sub1[j] = t1;
    key0 = n0; key1 = n1;
  }

  // Split weights once per launch.
  convertf32<<<(3 * KH * KH / 4 + 255) / 256, 256, 0, stream>>>(w_ih, WihHi, WihLo, 3 * KH * KH / 4);
  convertf32<<<(3 * KH * KH / 4 + 255) / 256, 256, 0, stream>>>(w_hh, WhhHi, WhhLo, 3 * KH * KH / 4);
  convert_hi<<<(KA * KH / 4 + 255) / 256, 256, 0, stream>>>(head_w, HwHi, KA * KH / 4);

  for (int j = 0; j < KL; ++j) {
    if (j == 0)
      convertf32<<<(KB * KH / 4 + 255) / 256, 256, 0, stream>>>(cls, Xhi, Xlo, KB * KH / 4);
    else
      build_x<<<KB * KH / 4 / 256, 256, 0, stream>>>(cls, ae_w, idxbuf, Xhi, Xlo);
    // gi (+ gh when j>0) in ONE dispatch over the concatenated A rows.
    gemm3_cat<<<dim3(3 * KH / 128, j == 0 ? 32 : 64), 256, 0, stream>>>(
        XhiCat, XloCat, WihHi, WihLo, WhhHi, WhhLo, Gi, Gh);
    gru_gate<<<KB * KH / 256, 256, 0, stream>>>(Gi, Gh, b_ih, b_hh, hbuf, hHi, hLo, j == 0);
    // approx logits (bf16 single product) straight into d_out[:, j, :]
    gemm1_nt<<<dim3(KA / 128, KB / 128), 256, 0, stream>>>(hHi, HwHi,
                                                           out + (size_t)j * KA, (long long)KL * KA);
    sample_step<<<KB, 256, 0, stream>>>(out, head_b, x_, mask, idxbuf, hbuf,
                                        head_w, j, sub0[j], sub1[j]);
  }
}